// Round 2
// baseline (250.407 us; speedup 1.0000x reference)
//
#include <hip/hip_runtime.h>
#include <hip/hip_bf16.h>

typedef __bf16 bf16x8 __attribute__((ext_vector_type(8)));
typedef __bf16 bf16x4 __attribute__((ext_vector_type(4)));
typedef short  s16x4  __attribute__((ext_vector_type(4)));
typedef float  f32x4  __attribute__((ext_vector_type(4)));

#define B_ 256
#define N_ 256
#define D_ 128
#define PSRC 136                                  // row-major LDS pitch (bf16 elems)
#define OFF_SRCT (N_ * PSRC * 2)                  // 69632
#define LDS_BYTES (OFF_SRCT + D_ * 512)           // 135168

// D = A*B + C for 16x16x16 bf16. A: m=lane&15, k=(lane>>4)*4+e. B: n=lane&15, same k.
// C/D: col=lane&15 (n), row=(lane>>4)*4+reg (m).
__device__ __forceinline__ f32x4 mfma16(bf16x4 a, bf16x4 b, f32x4 c) {
#if __has_builtin(__builtin_amdgcn_mfma_f32_16x16x16bf16_1k)
    union { bf16x4 h; s16x4 s; } ua, ub;
    ua.h = a; ub.h = b;
    return __builtin_amdgcn_mfma_f32_16x16x16bf16_1k(ua.s, ub.s, c, 0, 0, 0);
#else
    asm volatile("v_mfma_f32_16x16x16_bf16 %0, %1, %2, %0" : "+v"(c) : "v"(a), "v"(b));
    return c;
#endif
}

__global__ __launch_bounds__(512, 2) void gat_fused(
    const float* __restrict__ src, const int* __restrict__ adj,
    const float* __restrict__ a0, const float* __restrict__ a1,
    const float* __restrict__ a2, const float* __restrict__ a3,
    const float* __restrict__ bias, float* __restrict__ out)
{
    extern __shared__ char lds[];
    __bf16* s_src  = (__bf16*)lds;                // [256][136] bf16 row-major
    char*   s_srcT = lds + OFF_SRCT;              // [128][256] bf16, XOR-swizzled rows
    const int t    = threadIdx.x;
    const int lane = t & 63;
    const int wave = t >> 6;
    const int g    = lane >> 4;                   // 0..3
    const int r16  = lane & 15;                   // 0..15

    const int b = blockIdx.x;
    const float* __restrict__ srcb = src + (size_t)b * (N_ * D_);
    const int*   __restrict__ adjb = adj + (size_t)b * (N_ * N_);
    float*       __restrict__ outb = out + (size_t)b * (N_ * D_);

    // ---- adj prefetch for half 0 (issued BEFORE staging; hides HBM latency) ----
    // lane owns row i = wave*16 + r16; per jt: 4 consecutive j = jt*16 + g*4 .. +3
    int4 adjv[16];
    {
        const int4* __restrict__ ap = (const int4*)(adjb + (wave * 16 + r16) * N_ + g * 4);
        #pragma unroll
        for (int jt = 0; jt < 16; ++jt) adjv[jt] = ap[jt * 4];
    }

    // ---------------- stage src[b]: row-major bf16 + swizzled transpose ----------------
    {
        const int d   = t & 127;
        const int jb  = (t >> 7) * 64;
        const int swz = (d & 7) << 4;
        #pragma unroll
        for (int jo = 0; jo < 64; jo += 16) {
            float v[16];
            #pragma unroll
            for (int q = 0; q < 16; ++q) v[q] = srcb[(jb + jo + q) * D_ + d];
            #pragma unroll
            for (int q = 0; q < 16; ++q) s_src[(jb + jo + q) * PSRC + d] = (__bf16)v[q];
            #pragma unroll
            for (int q = 0; q < 16; q += 4) {
                bf16x4 w;
                w[0] = (__bf16)v[q];     w[1] = (__bf16)v[q + 1];
                w[2] = (__bf16)v[q + 2]; w[3] = (__bf16)v[q + 3];
                *(bf16x4*)(s_srcT + (d * 512 + ((2 * (jb + jo + q)) ^ swz))) = w;
            }
        }
    }
    __syncthreads();

    float bv[8];
    #pragma unroll
    for (int dt = 0; dt < 8; ++dt) bv[dt] = bias[dt * 16 + r16];
    const float* __restrict__ aptr[4] = {a0, a1, a2, a3};
    const int swzT = (r16 & 7) << 4;

    #pragma unroll 1
    for (int half = 0; half < 2; ++half) {
        const int i0 = half * 128 + wave * 16;    // this wave's 16 output rows

        // ---- B-fragments: bf16(src[i,:] * a_k) — lane r16 <-> row i (n index) ----
        bf16x8 asf[4][4];
        #pragma unroll
        for (int kc = 0; kc < 4; ++kc) {
            const bf16x8 base = *(const bf16x8*)&s_src[(i0 + r16) * PSRC + kc * 32 + g * 8];
            float bf[8];
            #pragma unroll
            for (int e = 0; e < 8; ++e) bf[e] = (float)base[e];
            #pragma unroll
            for (int k = 0; k < 4; ++k) {
                const float4 av0 = *(const float4*)(aptr[k] + kc * 32 + g * 8);
                const float4 av1 = *(const float4*)(aptr[k] + kc * 32 + g * 8 + 4);
                bf16x8 f;
                f[0] = (__bf16)(bf[0] * av0.x); f[1] = (__bf16)(bf[1] * av0.y);
                f[2] = (__bf16)(bf[2] * av0.z); f[3] = (__bf16)(bf[3] * av0.w);
                f[4] = (__bf16)(bf[4] * av1.x); f[5] = (__bf16)(bf[5] * av1.y);
                f[6] = (__bf16)(bf[6] * av1.z); f[7] = (__bf16)(bf[7] * av1.w);
                asf[k][kc] = f;
            }
        }

        // ---- QK^T swapped: A = src rows j (m<->j), B = scaled rows i (n<->i) ----
        // acc: lane holds 4 j-values (row=g*4+reg) for ONE i (col=r16).
        float p[16][4];
        #pragma unroll
        for (int jt = 0; jt < 16; ++jt) {
            bf16x8 bfr[4];
            #pragma unroll
            for (int kc = 0; kc < 4; ++kc)
                bfr[kc] = *(const bf16x8*)&s_src[(jt * 16 + r16) * PSRC + kc * 32 + g * 8];
            f32x4 acc0 = {0,0,0,0}, acc1 = {0,0,0,0}, acc2 = {0,0,0,0}, acc3 = {0,0,0,0};
            #pragma unroll
            for (int kc = 0; kc < 4; ++kc) {
                acc0 = __builtin_amdgcn_mfma_f32_16x16x32_bf16(bfr[kc], asf[0][kc], acc0, 0, 0, 0);
                acc1 = __builtin_amdgcn_mfma_f32_16x16x32_bf16(bfr[kc], asf[1][kc], acc1, 0, 0, 0);
                acc2 = __builtin_amdgcn_mfma_f32_16x16x32_bf16(bfr[kc], asf[2][kc], acc2, 0, 0, 0);
                acc3 = __builtin_amdgcn_mfma_f32_16x16x32_bf16(bfr[kc], asf[3][kc], acc3, 0, 0, 0);
            }
            const int4 av = adjv[jt];
            const int ac[4] = {av.x, av.y, av.z, av.w};
            #pragma unroll
            for (int r = 0; r < 4; ++r) {
                float v = -3.402823466e38f;
                v = (ac[r] == 1) ? acc0[r] : v;
                v = (ac[r] == 2) ? acc1[r] : v;
                v = (ac[r] == 3) ? acc2[r] : v;
                v = (ac[r] == 4) ? acc3[r] : v;
                p[jt][r] = fmaxf(v, 0.2f * v);     // leaky_relu
            }
        }

        // ---- issue adj prefetch for half 1 (overlaps softmax + PV) ----
        if (half == 0) {
            const int4* __restrict__ ap =
                (const int4*)(adjb + (128 + wave * 16 + r16) * N_ + g * 4);
            #pragma unroll
            for (int jt = 0; jt < 16; ++jt) adjv[jt] = ap[jt * 4];
        }

        // ---- row softmax: lane owns row i = i0 + r16; reduce in-lane then g-groups ----
        float mm = p[0][0];
        #pragma unroll
        for (int jt = 0; jt < 16; ++jt) {
            #pragma unroll
            for (int r = 0; r < 4; ++r) mm = fmaxf(mm, p[jt][r]);
        }
        mm = fmaxf(mm, __shfl_xor(mm, 16));
        mm = fmaxf(mm, __shfl_xor(mm, 32));
        float s = 0.f;
        #pragma unroll
        for (int jt = 0; jt < 16; ++jt) {
            #pragma unroll
            for (int r = 0; r < 4; ++r) {
                const float e = __builtin_exp2f((p[jt][r] - mm) * 1.4426950408889634f);
                p[jt][r] = e;
                s += e;
            }
        }
        s += __shfl_xor(s, 16);
        s += __shfl_xor(s, 32);
        const float sc = 1.0f / s;                 // fold normalization into P frags

        bf16x4 pb[16];                             // PV A-frags, directly in layout
        #pragma unroll
        for (int jt = 0; jt < 16; ++jt) {
            bf16x4 f;
            f[0] = (__bf16)(p[jt][0] * sc); f[1] = (__bf16)(p[jt][1] * sc);
            f[2] = (__bf16)(p[jt][2] * sc); f[3] = (__bf16)(p[jt][3] * sc);
            pb[jt] = f;
        }

        // ---- PV: out[i,d] = sum_j alpha[i,j] src[j,d] — B from srcT (b64, reg A) ----
        f32x4 oacc[8];
        #pragma unroll
        for (int dt = 0; dt < 8; ++dt) oacc[dt] = (f32x4){0, 0, 0, 0};
        asm volatile("s_nop 1" :::);               // VALU->MFMA srcC guard (asm path)
        #pragma unroll
        for (int jt = 0; jt < 16; ++jt) {
            const int jb2 = 32 * jt + 8 * g;       // byte offset of lane's 4 j's in a row
            #pragma unroll
            for (int dt = 0; dt < 8; ++dt) {
                const int d = dt * 16 + r16;
                const bf16x4 vf = *(const bf16x4*)(s_srcT + (d * 512 + (jb2 ^ swzT)));
                oacc[dt] = mfma16(pb[jt], vf, oacc[dt]);
            }
        }
        asm volatile("s_nop 7\n\ts_nop 7" :::);    // MFMA->VALU read hazard guard

        // ---- epilogue: bias add, coalesced f32 stores (rows i0+g*4+r, col d) ----
        #pragma unroll
        for (int dt = 0; dt < 8; ++dt) {
            #pragma unroll
            for (int r = 0; r < 4; ++r) {
                outb[(i0 + g * 4 + r) * D_ + dt * 16 + r16] = oacc[dt][r] + bv[dt];
            }
        }
    }
}

extern "C" void kernel_launch(void* const* d_in, const int* in_sizes, int n_in,
                              void* d_out, int out_size, void* d_ws, size_t ws_size,
                              hipStream_t stream) {
    const float* src  = (const float*)d_in[0];
    const int*   adj  = (const int*)d_in[1];
    const float* a0   = (const float*)d_in[2];
    const float* a1   = (const float*)d_in[3];
    const float* a2   = (const float*)d_in[4];
    const float* a3   = (const float*)d_in[5];
    const float* bias = (const float*)d_in[6];
    float* out = (float*)d_out;

    (void)hipFuncSetAttribute((const void*)gat_fused,
                              hipFuncAttributeMaxDynamicSharedMemorySize, LDS_BYTES);
    gat_fused<<<B_, 512, LDS_BYTES, stream>>>(src, adj, a0, a1, a2, a3, bias, out);
}

// Round 3
// 146.161 us; speedup vs baseline: 1.7132x; 1.7132x over previous
//
#include <hip/hip_runtime.h>
#include <hip/hip_bf16.h>

typedef __bf16 bf16x8 __attribute__((ext_vector_type(8)));
typedef __bf16 bf16x4 __attribute__((ext_vector_type(4)));
typedef short  s16x4  __attribute__((ext_vector_type(4)));
typedef float  f32x4  __attribute__((ext_vector_type(4)));

#define B_ 256
#define N_ 256
#define D_ 128
#define PSRC 136                                  // row-major LDS pitch (bf16 elems)
#define OFF_SRCT (N_ * PSRC * 2)                  // 69632
#define LDS_BYTES (OFF_SRCT + D_ * 512)           // 135168

// 16x16x16 bf16 MFMA. A: m=lane&15, k=(lane>>4)*4+e. B: n=lane&15, same k.
// C/D: col=lane&15 (n), row=(lane>>4)*4+reg (m).
__device__ __forceinline__ f32x4 mfma16(bf16x4 a, bf16x4 b, f32x4 c) {
#if __has_builtin(__builtin_amdgcn_mfma_f32_16x16x16bf16_1k)
    union { bf16x4 h; s16x4 s; } ua, ub;
    ua.h = a; ub.h = b;
    return __builtin_amdgcn_mfma_f32_16x16x16bf16_1k(ua.s, ub.s, c, 0, 0, 0);
#else
    asm volatile("v_mfma_f32_16x16x16_bf16 %0, %1, %2, %0" : "+v"(c) : "v"(a), "v"(b));
    return c;
#endif
}

__global__ __launch_bounds__(512, 2) void gat_fused(
    const float* __restrict__ src, const int* __restrict__ adj,
    const float* __restrict__ a0, const float* __restrict__ a1,
    const float* __restrict__ a2, const float* __restrict__ a3,
    const float* __restrict__ bias, float* __restrict__ out)
{
    extern __shared__ char lds[];
    __bf16* s_src  = (__bf16*)lds;                // [256][136] bf16 row-major
    char*   s_srcT = lds + OFF_SRCT;              // [128][256] bf16, XOR-swizzled rows
    const int t    = threadIdx.x;
    const int lane = t & 63;
    const int wave = t >> 6;
    const int g    = lane >> 4;                   // 0..3
    const int r16  = lane & 15;                   // 0..15

    const int b = blockIdx.x;
    const float* __restrict__ srcb = src + (size_t)b * (N_ * D_);
    const int*   __restrict__ adjb = adj + (size_t)b * (N_ * N_);
    float*       __restrict__ outb = out + (size_t)b * (N_ * D_);

    // ---- rolling adj prefetch, depth 4 (lane owns row i = wave*16+r16, cols g*4..+3) ----
    int4 adjq[4];
    {
        const int4* __restrict__ ap = (const int4*)(adjb + (wave * 16 + r16) * N_ + g * 4);
        adjq[0] = ap[0]; adjq[1] = ap[4]; adjq[2] = ap[8]; adjq[3] = ap[12];
    }

    // ---------------- stage src[b]: row-major bf16 + swizzled transpose ----------------
    {
        const int d   = t & 127;
        const int jb  = (t >> 7) * 64;
        const int swz = (d & 7) << 4;
        #pragma unroll
        for (int jo = 0; jo < 64; jo += 16) {
            float v[16];
            #pragma unroll
            for (int q = 0; q < 16; ++q) v[q] = srcb[(jb + jo + q) * D_ + d];
            #pragma unroll
            for (int q = 0; q < 16; ++q) s_src[(jb + jo + q) * PSRC + d] = (__bf16)v[q];
            #pragma unroll
            for (int q = 0; q < 16; q += 4) {
                bf16x4 w;
                w[0] = (__bf16)v[q];     w[1] = (__bf16)v[q + 1];
                w[2] = (__bf16)v[q + 2]; w[3] = (__bf16)v[q + 3];
                *(bf16x4*)(s_srcT + (d * 512 + ((2 * (jb + jo + q)) ^ swz))) = w;
            }
        }
    }
    __syncthreads();

    float bv[8];
    #pragma unroll
    for (int dt = 0; dt < 8; ++dt) bv[dt] = bias[dt * 16 + r16];
    const float* __restrict__ aptr[4] = {a0, a1, a2, a3};
    const int swzT = (r16 & 7) << 4;

    #pragma unroll 1
    for (int half = 0; half < 2; ++half) {
        const int i0 = half * 128 + wave * 16;    // this wave's 16 output rows

        // ---- B-fragments: bf16(src[i,:] * a_k) — lane r16 <-> row i (n index) ----
        bf16x8 asf[4][4];
        #pragma unroll
        for (int kc = 0; kc < 4; ++kc) {
            const bf16x8 base = *(const bf16x8*)&s_src[(i0 + r16) * PSRC + kc * 32 + g * 8];
            float bf[8];
            #pragma unroll
            for (int e = 0; e < 8; ++e) bf[e] = (float)base[e];
            #pragma unroll
            for (int k = 0; k < 4; ++k) {
                const float4 av0 = *(const float4*)(aptr[k] + kc * 32 + g * 8);
                const float4 av1 = *(const float4*)(aptr[k] + kc * 32 + g * 8 + 4);
                bf16x8 f;
                f[0] = (__bf16)(bf[0] * av0.x); f[1] = (__bf16)(bf[1] * av0.y);
                f[2] = (__bf16)(bf[2] * av0.z); f[3] = (__bf16)(bf[3] * av0.w);
                f[4] = (__bf16)(bf[4] * av1.x); f[5] = (__bf16)(bf[5] * av1.y);
                f[6] = (__bf16)(bf[6] * av1.z); f[7] = (__bf16)(bf[7] * av1.w);
                asf[k][kc] = f;
            }
        }

        // ---- QK^T swapped: A = src rows j (m<->j), B = scaled rows i (n<->i) ----
        // acc: lane holds 4 j-values (row=g*4+reg) for ONE i (col=r16).
        float p[16][4];
        #pragma unroll
        for (int jt = 0; jt < 16; ++jt) {
            const int4 av = adjq[jt & 3];
            // rolling prefetch: this half's jt+4, or next half's jt-12
            if (jt < 12) {
                adjq[jt & 3] = *(const int4*)(adjb +
                    (i0 + r16) * N_ + (jt + 4) * 16 + g * 4);
            } else if (half == 0) {
                adjq[jt & 3] = *(const int4*)(adjb +
                    (128 + wave * 16 + r16) * N_ + (jt - 12) * 16 + g * 4);
            }
            bf16x8 bfr[4];
            #pragma unroll
            for (int kc = 0; kc < 4; ++kc)
                bfr[kc] = *(const bf16x8*)&s_src[(jt * 16 + r16) * PSRC + kc * 32 + g * 8];
            f32x4 acc0 = {0,0,0,0}, acc1 = {0,0,0,0}, acc2 = {0,0,0,0}, acc3 = {0,0,0,0};
            #pragma unroll
            for (int kc = 0; kc < 4; ++kc) {
                acc0 = __builtin_amdgcn_mfma_f32_16x16x32_bf16(bfr[kc], asf[0][kc], acc0, 0, 0, 0);
                acc1 = __builtin_amdgcn_mfma_f32_16x16x32_bf16(bfr[kc], asf[1][kc], acc1, 0, 0, 0);
                acc2 = __builtin_amdgcn_mfma_f32_16x16x32_bf16(bfr[kc], asf[2][kc], acc2, 0, 0, 0);
                acc3 = __builtin_amdgcn_mfma_f32_16x16x32_bf16(bfr[kc], asf[3][kc], acc3, 0, 0, 0);
            }
            const int ac[4] = {av.x, av.y, av.z, av.w};
            #pragma unroll
            for (int r = 0; r < 4; ++r) {
                float v = -3.402823466e38f;
                v = (ac[r] == 1) ? acc0[r] : v;
                v = (ac[r] == 2) ? acc1[r] : v;
                v = (ac[r] == 3) ? acc2[r] : v;
                v = (ac[r] == 4) ? acc3[r] : v;
                p[jt][r] = fmaxf(v, 0.2f * v);     // leaky_relu
            }
        }

        // ---- row softmax: lane owns row i = i0 + r16; reduce in-lane then across g ----
        float mm = p[0][0];
        #pragma unroll
        for (int jt = 0; jt < 16; ++jt) {
            #pragma unroll
            for (int r = 0; r < 4; ++r) mm = fmaxf(mm, p[jt][r]);
        }
        mm = fmaxf(mm, __shfl_xor(mm, 16));
        mm = fmaxf(mm, __shfl_xor(mm, 32));
        float s = 0.f;
        #pragma unroll
        for (int jt = 0; jt < 16; ++jt) {
            #pragma unroll
            for (int r = 0; r < 4; ++r) {
                const float e = __builtin_exp2f((p[jt][r] - mm) * 1.4426950408889634f);
                p[jt][r] = e;
                s += e;
            }
        }
        s += __shfl_xor(s, 16);
        s += __shfl_xor(s, 32);
        const float sc = 1.0f / s;                 // fold normalization into P frags

        // ---- PV: out[i,d] = sum_j alpha[i,j] src[j,d]; P→bf16 on the fly ----
        f32x4 oacc[8];
        #pragma unroll
        for (int dt = 0; dt < 8; ++dt) oacc[dt] = (f32x4){0, 0, 0, 0};
        #pragma unroll
        for (int jt = 0; jt < 16; ++jt) {
            bf16x4 pf;
            pf[0] = (__bf16)(p[jt][0] * sc); pf[1] = (__bf16)(p[jt][1] * sc);
            pf[2] = (__bf16)(p[jt][2] * sc); pf[3] = (__bf16)(p[jt][3] * sc);
            const int jb2 = 32 * jt + 8 * g;       // byte offset of lane's 4 j's in a row
            #pragma unroll
            for (int dt = 0; dt < 8; ++dt) {
                const int d = dt * 16 + r16;
                const bf16x4 vf = *(const bf16x4*)(s_srcT + (d * 512 + (jb2 ^ swzT)));
                oacc[dt] = mfma16(pf, vf, oacc[dt]);
            }
        }
        asm volatile("s_nop 7\n\ts_nop 7" :::);    // MFMA->VALU read hazard guard

        // ---- epilogue: bias add, coalesced f32 stores (rows i0+g*4+r, col d) ----
        #pragma unroll
        for (int dt = 0; dt < 8; ++dt) {
            #pragma unroll
            for (int r = 0; r < 4; ++r) {
                outb[(i0 + g * 4 + r) * D_ + dt * 16 + r16] = oacc[dt][r] + bv[dt];
            }
        }
    }
}

extern "C" void kernel_launch(void* const* d_in, const int* in_sizes, int n_in,
                              void* d_out, int out_size, void* d_ws, size_t ws_size,
                              hipStream_t stream) {
    const float* src  = (const float*)d_in[0];
    const int*   adj  = (const int*)d_in[1];
    const float* a0   = (const float*)d_in[2];
    const float* a1   = (const float*)d_in[3];
    const float* a2   = (const float*)d_in[4];
    const float* a3   = (const float*)d_in[5];
    const float* bias = (const float*)d_in[6];
    float* out = (float*)d_out;

    (void)hipFuncSetAttribute((const void*)gat_fused,
                              hipFuncAttributeMaxDynamicSharedMemorySize, LDS_BYTES);
    gat_fused<<<B_, 512, LDS_BYTES, stream>>>(src, adj, a0, a1, a2, a3, bias, out);
}